// Round 1
// 276.098 us; speedup vs baseline: 1.0124x; 1.0124x over previous
//
#include <hip/hip_runtime.h>
#include <math.h>

// Problem constants: N=50000, E=800000, IN=128, OUT=64, H1=2, H2=1
#define NNODES 50000
#define NEDGES 800000

typedef short bf16x8 __attribute__((ext_vector_type(8)));
typedef float f32x4  __attribute__((ext_vector_type(4)));

// ---- manual bf16 pack/unpack (plain uint words) ----
__device__ __forceinline__ unsigned bfpack(float a, float b) {
    unsigned ua = __float_as_uint(a), ub = __float_as_uint(b);
    ua = (ua + 0x7fffu + ((ua >> 16) & 1u)) >> 16;
    ub = (ub + 0x7fffu + ((ub >> 16) & 1u)) >> 16;
    return ua | (ub << 16);
}
__device__ __forceinline__ float bflo(unsigned u) { return __uint_as_float(u << 16); }
__device__ __forceinline__ float bfhi(unsigned u) { return __uint_as_float(u & 0xffff0000u); }

// ---------------- CSR build (by dst; shared by both layers) ----------------

__global__ __launch_bounds__(256) void hist_kernel(const int* __restrict__ dst,
                                                   int* __restrict__ deg) {
    int e = blockIdx.x * 256 + threadIdx.x;
    if (e < NEDGES) atomicAdd(&deg[dst[e]], 1);
}

__global__ __launch_bounds__(256) void alloc_kernel(const int* __restrict__ deg,
                                                    int* __restrict__ total,
                                                    int* __restrict__ rowptr,
                                                    int* __restrict__ cursor) {
    const int i = blockIdx.x * 256 + threadIdx.x;
    const int lane = threadIdx.x & 63;
    int d = (i < NNODES) ? deg[i] : 0;
    int incl = d;
#pragma unroll
    for (int off = 1; off < 64; off <<= 1) {
        int t = __shfl_up(incl, off);
        if (lane >= off) incl += t;
    }
    int base = 0;
    if (lane == 63) base = atomicAdd(total, incl);
    base = __shfl(base, 63);
    if (i < NNODES) {
        int pos = base + incl - d;
        rowptr[i] = pos;
        cursor[i] = pos;
    }
}

__global__ __launch_bounds__(256) void fill_kernel(
    const int* __restrict__ src, const int* __restrict__ dst,
    int* __restrict__ cursor, unsigned short* __restrict__ csr_src) {
    int e = blockIdx.x * 256 + threadIdx.x;
    if (e < NEDGES) {
        int pos = atomicAdd(&cursor[dst[e]], 1);
        csr_src[pos] = (unsigned short)src[e];
    }
}

// ---------------- weight prep: W1^T and W2^T packed bf16 -------------------
__global__ __launch_bounds__(256) void wt_kernel(const float* __restrict__ W1,
                                                 const float* __restrict__ W2,
                                                 unsigned* __restrict__ W1t,
                                                 unsigned* __restrict__ W2t) {
    int w = blockIdx.x * 256 + threadIdx.x;   // 0..12287
    if (w < 8192) {
        int n = w >> 6, j = w & 63;
        W1t[w] = bfpack(W1[(2 * j) * 128 + n], W1[(2 * j + 1) * 128 + n]);
    } else {
        int w2 = w - 8192;
        int n = w2 >> 6, j = w2 & 63;
        W2t[w2] = bfpack(W2[(2 * j) * 64 + n], W2[(2 * j + 1) * 64 + n]);
    }
}

// ---------------- gemm1: MFMA bf16 ----------------
__global__ __launch_bounds__(256) void gemm1_kernel(
    const float* __restrict__ feat, const unsigned* __restrict__ Wt,
    const float* __restrict__ al, const float* __restrict__ ar,
    unsigned* __restrict__ h, float* __restrict__ el, float* __restrict__ er) {
    __shared__ unsigned Wb[128 * 68];
    __shared__ unsigned Ab[64 * 68];
    const int tid = threadIdx.x;
    const int n0  = blockIdx.x * 64;

#pragma unroll
    for (int i = 0; i < 8; ++i) {
        int id = i * 256 + tid;
        int n = id >> 4, c = (id & 15) * 4;
        *(uint4*)&Wb[n * 68 + c] = *(const uint4*)&Wt[n * 64 + c];
    }
#pragma unroll
    for (int i = 0; i < 8; ++i) {
        int f = i * 256 + tid;
        int m = f >> 5, cf = (f & 31) * 4;
        float4 v = make_float4(0.f, 0.f, 0.f, 0.f);
        if (n0 + m < NNODES)
            v = *(const float4*)&feat[(size_t)(n0 + m) * 128 + cf];
        uint2 p = {bfpack(v.x, v.y), bfpack(v.z, v.w)};
        *(uint2*)&Ab[m * 68 + cf / 2] = p;
    }
    __syncthreads();

    const int w  = tid >> 6;
    const int l  = tid & 63;
    const int ml = l & 15;
    const int q  = l >> 4;
    f32x4 acc[8];
#pragma unroll
    for (int t = 0; t < 8; ++t) acc[t] = (f32x4){0.f, 0.f, 0.f, 0.f};

#pragma unroll
    for (int kc = 0; kc < 4; ++kc) {
        const int kw = kc * 16 + q * 4;
        uint4 a4 = *(uint4*)&Ab[(16 * w + ml) * 68 + kw];
        bf16x8 af = *(bf16x8*)&a4;
#pragma unroll
        for (int t = 0; t < 8; ++t) {
            uint4 b4 = *(uint4*)&Wb[(t * 16 + ml) * 68 + kw];
            bf16x8 bf = *(bf16x8*)&b4;
            acc[t] = __builtin_amdgcn_mfma_f32_16x16x32_bf16(af, bf, acc[t], 0, 0, 0);
        }
    }

    float av[8], rv[8];
#pragma unroll
    for (int t = 0; t < 8; ++t) { av[t] = al[t * 16 + ml]; rv[t] = ar[t * 16 + ml]; }

#pragma unroll
    for (int r = 0; r < 4; ++r) {
        const int node = n0 + 16 * w + q * 4 + r;
        float e0 = 0.f, e1 = 0.f, f0 = 0.f, f1 = 0.f;
#pragma unroll
        for (int t = 0; t < 8; ++t) {
            float v = acc[t][r];
            if (t < 4) { e0 = fmaf(v, av[t], e0); f0 = fmaf(v, rv[t], f0); }
            else       { e1 = fmaf(v, av[t], e1); f1 = fmaf(v, rv[t], f1); }
            float pv = __shfl_xor(v, 1);
            if ((ml & 1) == 0 && node < NNODES)
                h[(size_t)node * 64 + t * 8 + (ml >> 1)] = bfpack(v, pv);
        }
#pragma unroll
        for (int mm = 1; mm <= 8; mm <<= 1) {
            e0 += __shfl_xor(e0, mm); e1 += __shfl_xor(e1, mm);
            f0 += __shfl_xor(f0, mm); f1 += __shfl_xor(f1, mm);
        }
        if (ml == 0 && node < NNODES) {
            el[node * 2 + 0] = e0; el[node * 2 + 1] = e1;
            er[node * 2 + 0] = f0; er[node * 2 + 1] = f1;
        }
    }
}

// ---------------- gemm2: MFMA bf16, A read directly as packed bf16 ---------
__global__ __launch_bounds__(256) void gemm2_kernel(
    const unsigned* __restrict__ h1b, const unsigned* __restrict__ Wt,
    const float* __restrict__ al, const float* __restrict__ ar,
    unsigned* __restrict__ h2, float* __restrict__ el, float* __restrict__ er) {
    __shared__ unsigned Wb[64 * 68];
    __shared__ unsigned Ab[64 * 68];
    const int tid = threadIdx.x;
    const int n0  = blockIdx.x * 64;

    // stage W2^T: 4096 words = 1024 uint4
#pragma unroll
    for (int i = 0; i < 4; ++i) {
        int id = i * 256 + tid;
        int n = id >> 4, c = (id & 15) * 4;
        *(uint4*)&Wb[n * 68 + c] = *(const uint4*)&Wt[n * 64 + c];
    }
    // stage A: already bf16-packed in k-pair layout; 1024 uint4
#pragma unroll
    for (int i = 0; i < 4; ++i) {
        int id = i * 256 + tid;
        int m = id >> 4, c = (id & 15) * 4;
        uint4 v = make_uint4(0u, 0u, 0u, 0u);
        if (n0 + m < NNODES)
            v = *(const uint4*)&h1b[(size_t)(n0 + m) * 64 + c];
        *(uint4*)&Ab[m * 68 + c] = v;
    }
    __syncthreads();

    const int w  = tid >> 6;
    const int l  = tid & 63;
    const int ml = l & 15;
    const int q  = l >> 4;
    f32x4 acc[4];
#pragma unroll
    for (int t = 0; t < 4; ++t) acc[t] = (f32x4){0.f, 0.f, 0.f, 0.f};

#pragma unroll
    for (int kc = 0; kc < 4; ++kc) {
        const int kw = kc * 16 + q * 4;
        uint4 a4 = *(uint4*)&Ab[(16 * w + ml) * 68 + kw];
        bf16x8 af = *(bf16x8*)&a4;
#pragma unroll
        for (int t = 0; t < 4; ++t) {
            uint4 b4 = *(uint4*)&Wb[(t * 16 + ml) * 68 + kw];
            bf16x8 bf = *(bf16x8*)&b4;
            acc[t] = __builtin_amdgcn_mfma_f32_16x16x32_bf16(af, bf, acc[t], 0, 0, 0);
        }
    }

    float av[4], rv[4];
#pragma unroll
    for (int t = 0; t < 4; ++t) { av[t] = al[t * 16 + ml]; rv[t] = ar[t * 16 + ml]; }

#pragma unroll
    for (int r = 0; r < 4; ++r) {
        const int node = n0 + 16 * w + q * 4 + r;
        float e0 = 0.f, f0 = 0.f;
#pragma unroll
        for (int t = 0; t < 4; ++t) {
            float v = acc[t][r];
            e0 = fmaf(v, av[t], e0);
            f0 = fmaf(v, rv[t], f0);
            float pv = __shfl_xor(v, 1);
            if ((ml & 1) == 0 && node < NNODES)
                h2[(size_t)node * 32 + t * 8 + (ml >> 1)] = bfpack(v, pv);
        }
#pragma unroll
        for (int mm = 1; mm <= 8; mm <<= 1) {
            e0 += __shfl_xor(e0, mm);
            f0 += __shfl_xor(f0, mm);
        }
        if (ml == 0 && node < NNODES) { el[node] = e0; er[node] = f0; }
    }
}

#define FMA8(hv, A)                                              \
    a0r = fmaf(A, bflo(hv.x), a0r); a1r = fmaf(A, bfhi(hv.x), a1r); \
    a2r = fmaf(A, bflo(hv.y), a2r); a3r = fmaf(A, bfhi(hv.y), a3r); \
    a4r = fmaf(A, bflo(hv.z), a4r); a5r = fmaf(A, bfhi(hv.z), a5r); \
    a6r = fmaf(A, bflo(hv.w), a6r); a7r = fmaf(A, bfhi(hv.w), a7r);

// ---- layer-1 aggregate: 1 wave/node; branch-free gather, 4 loads in flight.
// Phantom edges (lane >= deg) have p==0, so loads are unguarded (s_reg=0 is a
// valid, cache-hot row) and FMAs add 0. Emits packed-bf16 h1 (gemm2 A layout)
// and the f32 head-mean (consumed by aggregate2's epilogue).
__global__ __launch_bounds__(256) void aggregate1_kernel(
    const int* __restrict__ rowptr, const int* __restrict__ degv,
    const unsigned short* __restrict__ csr_src,
    const float* __restrict__ el, const float* __restrict__ er,
    const unsigned* __restrict__ hh, const float* __restrict__ bias,
    unsigned* __restrict__ h1b, float* __restrict__ hm) {
    const int node = (blockIdx.x * 256 + threadIdx.x) >> 6;
    const int lane = threadIdx.x & 63;
    if (node >= NNODES) return;
    const int row = rowptr[node];
    const int deg = degv[node];
    const float er0 = er[node * 2 + 0];
    const float er1 = er[node * 2 + 1];

    int   s_reg = 0;
    float v0 = -1e30f, v1 = -1e30f;
    if (lane < deg) {
        s_reg = (int)csr_src[row + lane];
        float2 e = *(const float2*)&el[s_reg * 2];
        float a = e.x + er0; v0 = a > 0.f ? a : 0.2f * a;
        float b = e.y + er1; v1 = b > 0.f ? b : 0.2f * b;
    }
    float m0 = v0, m1 = v1;
    for (int i = 64 + lane; i < deg; i += 64) {
        int s = (int)csr_src[row + i];
        float2 e = *(const float2*)&el[s * 2];
        float a = e.x + er0; a = a > 0.f ? a : 0.2f * a;
        float b = e.y + er1; b = b > 0.f ? b : 0.2f * b;
        m0 = fmaxf(m0, a); m1 = fmaxf(m1, b);
    }
#pragma unroll
    for (int off = 32; off > 0; off >>= 1) {
        m0 = fmaxf(m0, __shfl_xor(m0, off));
        m1 = fmaxf(m1, __shfl_xor(m1, off));
    }

    float p0 = (lane < deg) ? __expf(v0 - m0) : 0.f;
    float p1 = (lane < deg) ? __expf(v1 - m1) : 0.f;
    float ssum0 = p0, ssum1 = p1;
    for (int i = 64 + lane; i < deg; i += 64) {
        int s = (int)csr_src[row + i];
        float2 e = *(const float2*)&el[s * 2];
        float a = e.x + er0; a = a > 0.f ? a : 0.2f * a;
        float b = e.y + er1; b = b > 0.f ? b : 0.2f * b;
        ssum0 += __expf(a - m0); ssum1 += __expf(b - m1);
    }
#pragma unroll
    for (int off = 32; off > 0; off >>= 1) {
        ssum0 += __shfl_xor(ssum0, off);
        ssum1 += __shfl_xor(ssum1, off);
    }

    const int  q     = lane >> 4;
    const int  ql    = lane & 15;
    const bool h1sel = (ql >= 8);
    float a0r = 0.f, a1r = 0.f, a2r = 0.f, a3r = 0.f;
    float a4r = 0.f, a5r = 0.f, a6r = 0.f, a7r = 0.f;
    const unsigned* __restrict__ hq = hh + 4 * ql;
    const int dmax = deg < 64 ? deg : 64;
    const int nit  = (dmax + 3) & ~3;
    int i = 0;
    // main: 16 edges/iter, 4 independent gathers in flight
    for (; i + 12 < nit; i += 16) {
        const int e0 = i + q;
        int   sA = __shfl(s_reg, e0);      float xA = __shfl(p0, e0),      yA = __shfl(p1, e0);
        int   sB = __shfl(s_reg, e0 + 4);  float xB = __shfl(p0, e0 + 4),  yB = __shfl(p1, e0 + 4);
        int   sC = __shfl(s_reg, e0 + 8);  float xC = __shfl(p0, e0 + 8),  yC = __shfl(p1, e0 + 8);
        int   sD = __shfl(s_reg, e0 + 12); float xD = __shfl(p0, e0 + 12), yD = __shfl(p1, e0 + 12);
        uint4 hA = *(const uint4*)(hq + (size_t)sA * 64);
        uint4 hB = *(const uint4*)(hq + (size_t)sB * 64);
        uint4 hC = *(const uint4*)(hq + (size_t)sC * 64);
        uint4 hD = *(const uint4*)(hq + (size_t)sD * 64);
        float AA = h1sel ? yA : xA;
        float AB = h1sel ? yB : xB;
        float AC = h1sel ? yC : xC;
        float AD = h1sel ? yD : xD;
        FMA8(hA, AA)
        FMA8(hB, AB)
        FMA8(hC, AC)
        FMA8(hD, AD)
    }
    for (; i < nit; i += 4) {
        const int e0 = i + q;
        int   sA = __shfl(s_reg, e0);
        float xA = __shfl(p0, e0), yA = __shfl(p1, e0);
        uint4 hA = *(const uint4*)(hq + (size_t)sA * 64);
        float AA = h1sel ? yA : xA;
        FMA8(hA, AA)
    }
    // rare overflow (deg > 64)
    for (int i2 = 64; i2 < deg; i2 += 4) {
        int eidx = i2 + q;
        if (eidx < deg) {
            int s = (int)csr_src[row + eidx];
            float2 e = *(const float2*)&el[s * 2];
            float a = e.x + er0; a = a > 0.f ? a : 0.2f * a;
            float b = e.y + er1; b = b > 0.f ? b : 0.2f * b;
            float alpha = h1sel ? __expf(b - m1) : __expf(a - m0);
            uint4 hv = *(const uint4*)(hq + (size_t)s * 64);
            FMA8(hv, alpha)
        }
    }
    a0r += __shfl_xor(a0r, 16);  a1r += __shfl_xor(a1r, 16);
    a2r += __shfl_xor(a2r, 16);  a3r += __shfl_xor(a3r, 16);
    a4r += __shfl_xor(a4r, 16);  a5r += __shfl_xor(a5r, 16);
    a6r += __shfl_xor(a6r, 16);  a7r += __shfl_xor(a7r, 16);
    a0r += __shfl_xor(a0r, 32);  a1r += __shfl_xor(a1r, 32);
    a2r += __shfl_xor(a2r, 32);  a3r += __shfl_xor(a3r, 32);
    a4r += __shfl_xor(a4r, 32);  a5r += __shfl_xor(a5r, 32);
    a6r += __shfl_xor(a6r, 32);  a7r += __shfl_xor(a7r, 32);

    // epilogue: all lanes hold full sums (quads are duplicates after reduce)
    const float ssum = h1sel ? ssum1 : ssum0;
    const float inv  = (deg > 0) ? 1.f / ssum : 0.f;
    float4 b0 = *(const float4*)&bias[8 * ql];
    float4 b1 = *(const float4*)&bias[8 * ql + 4];
    float o0 = fmaf(a0r, inv, b0.x), o1 = fmaf(a1r, inv, b0.y);
    float o2 = fmaf(a2r, inv, b0.z), o3 = fmaf(a3r, inv, b0.w);
    float o4 = fmaf(a4r, inv, b1.x), o5 = fmaf(a5r, inv, b1.y);
    float o6 = fmaf(a6r, inv, b1.z), o7 = fmaf(a7r, inv, b1.w);
    o0 = o0 > 0.f ? o0 : (__expf(o0) - 1.f);
    o1 = o1 > 0.f ? o1 : (__expf(o1) - 1.f);
    o2 = o2 > 0.f ? o2 : (__expf(o2) - 1.f);
    o3 = o3 > 0.f ? o3 : (__expf(o3) - 1.f);
    o4 = o4 > 0.f ? o4 : (__expf(o4) - 1.f);
    o5 = o5 > 0.f ? o5 : (__expf(o5) - 1.f);
    o6 = o6 > 0.f ? o6 : (__expf(o6) - 1.f);
    o7 = o7 > 0.f ? o7 : (__expf(o7) - 1.f);

    if (lane < 16) {
        uint4 pk;
        pk.x = bfpack(o0, o1); pk.y = bfpack(o2, o3);
        pk.z = bfpack(o4, o5); pk.w = bfpack(o6, o7);
        *(uint4*)&h1b[(size_t)node * 64 + 4 * ql] = pk;
    }
    // head mean: lane l (<8) pairs with lane l+8 (head1, same dims)
    float n0_ = 0.5f * (o0 + __shfl_xor(o0, 8));
    float n1_ = 0.5f * (o1 + __shfl_xor(o1, 8));
    float n2_ = 0.5f * (o2 + __shfl_xor(o2, 8));
    float n3_ = 0.5f * (o3 + __shfl_xor(o3, 8));
    float n4_ = 0.5f * (o4 + __shfl_xor(o4, 8));
    float n5_ = 0.5f * (o5 + __shfl_xor(o5, 8));
    float n6_ = 0.5f * (o6 + __shfl_xor(o6, 8));
    float n7_ = 0.5f * (o7 + __shfl_xor(o7, 8));
    if (lane < 8) {
        *(float4*)&hm[(size_t)node * 64 + 8 * lane]     = make_float4(n0_, n1_, n2_, n3_);
        *(float4*)&hm[(size_t)node * 64 + 8 * lane + 4] = make_float4(n4_, n5_, n6_, n7_);
    }
}

#define FMA4(hv, P)                                            \
    ax = fmaf(P, bflo(hv.x), ax); ay = fmaf(P, bfhi(hv.x), ay); \
    az = fmaf(P, bflo(hv.y), az); aw = fmaf(P, bfhi(hv.y), aw);

// ---- layer-2 aggregate: 2 nodes/wave; branch-free gather, 4 loads in flight
__global__ __launch_bounds__(256) void aggregate2_kernel(
    const int* __restrict__ rowptr, const int* __restrict__ degv,
    const unsigned short* __restrict__ csr_src,
    const float* __restrict__ el, const float* __restrict__ er,
    const unsigned* __restrict__ hh, const float* __restrict__ bias,
    const float* __restrict__ hm, float* __restrict__ outp) {
    const int wid  = (blockIdx.x * 256 + threadIdx.x) >> 6;
    const int lane = threadIdx.x & 63;
    const int hl   = lane & 31;
    const int node = wid * 2 + (lane >> 5);
    if (node >= NNODES) return;
    const int row = rowptr[node];
    const int deg = degv[node];
    const float erd = er[node];

    int   s_reg = 0;
    float v_reg = -1e30f;
    if (hl < deg) {
        s_reg = (int)csr_src[row + hl];
        float v = el[s_reg] + erd;
        v_reg = v > 0.f ? v : 0.2f * v;
    }
    float m = v_reg;
    for (int i = 32 + hl; i < deg; i += 32) {
        int s = (int)csr_src[row + i];
        float v = el[s] + erd;
        v = v > 0.f ? v : 0.2f * v;
        m = fmaxf(m, v);
    }
#pragma unroll
    for (int off = 16; off > 0; off >>= 1) m = fmaxf(m, __shfl_xor(m, off));

    float p_reg = (hl < deg) ? __expf(v_reg - m) : 0.f;
    float ssum = p_reg;
    for (int i = 32 + hl; i < deg; i += 32) {
        int s = (int)csr_src[row + i];
        float v = el[s] + erd;
        v = v > 0.f ? v : 0.2f * v;
        ssum += __expf(v - m);
    }
#pragma unroll
    for (int off = 16; off > 0; off >>= 1) ssum += __shfl_xor(ssum, off);

    const int s2 = hl >> 4;
    const int sl = hl & 15;
    const int lb = lane & 32;
    float ax = 0.f, ay = 0.f, az = 0.f, aw = 0.f;
    const int dmax = deg < 32 ? deg : 32;
    int dmW = dmax;
    dmW = max(dmW, __shfl_xor(dmW, 32));
    const int nit = (dmW + 1) & ~1;
    const unsigned* __restrict__ hq = hh + 2 * sl;
    int i = 0;
    for (; i + 6 < nit; i += 8) {
        const int e0 = lb + i + s2;
        int sA = __shfl(s_reg, e0);     float pA = __shfl(p_reg, e0);
        int sB = __shfl(s_reg, e0 + 2); float pB = __shfl(p_reg, e0 + 2);
        int sC = __shfl(s_reg, e0 + 4); float pC = __shfl(p_reg, e0 + 4);
        int sD = __shfl(s_reg, e0 + 6); float pD = __shfl(p_reg, e0 + 6);
        uint2 hA = *(const uint2*)(hq + (size_t)sA * 32);
        uint2 hB = *(const uint2*)(hq + (size_t)sB * 32);
        uint2 hC = *(const uint2*)(hq + (size_t)sC * 32);
        uint2 hD = *(const uint2*)(hq + (size_t)sD * 32);
        FMA4(hA, pA)
        FMA4(hB, pB)
        FMA4(hC, pC)
        FMA4(hD, pD)
    }
    for (; i < nit; i += 2) {
        const int e0 = lb + i + s2;
        int sA = __shfl(s_reg, e0); float pA = __shfl(p_reg, e0);
        uint2 hA = *(const uint2*)(hq + (size_t)sA * 32);
        FMA4(hA, pA)
    }
    for (int i2 = 32; i2 < deg; i2 += 2) {
        int eidx = i2 + s2;
        if (eidx < deg) {
            int s = (int)csr_src[row + eidx];
            float v = el[s] + erd;
            v = v > 0.f ? v : 0.2f * v;
            float p = __expf(v - m);
            uint2 hv = *(const uint2*)(hq + (size_t)s * 32);
            FMA4(hv, p)
        }
    }
    ax += __shfl_xor(ax, 16);  ay += __shfl_xor(ay, 16);
    az += __shfl_xor(az, 16);  aw += __shfl_xor(aw, 16);

    if (sl == hl) {
        float inv = (deg > 0) ? 1.f / ssum : 0.f;
        float4 hmv = *(const float4*)&hm[(size_t)node * 64 + 4 * sl];
        float4 bb  = *(const float4*)&bias[4 * sl];
        float o0 = (hmv.x + fmaf(ax, inv, bb.x)) * 0.5f;
        float o1 = (hmv.y + fmaf(ay, inv, bb.y)) * 0.5f;
        float o2 = (hmv.z + fmaf(az, inv, bb.z)) * 0.5f;
        float o3 = (hmv.w + fmaf(aw, inv, bb.w)) * 0.5f;
        *(float4*)&outp[(size_t)node * 64 + 4 * sl] = make_float4(o0, o1, o2, o3);
    }
}

// ---------------- launcher ----------------

extern "C" void kernel_launch(void* const* d_in, const int* in_sizes, int n_in,
                              void* d_out, int out_size, void* d_ws, size_t ws_size,
                              hipStream_t stream) {
    const float* feat = (const float*)d_in[0];
    const int*   src  = (const int*)d_in[1];
    const int*   dst  = (const int*)d_in[2];
    const float* W1   = (const float*)d_in[3];
    const float* al1  = (const float*)d_in[4];
    const float* ar1  = (const float*)d_in[5];
    const float* b1   = (const float*)d_in[6];
    const float* W2   = (const float*)d_in[7];
    const float* al2  = (const float*)d_in[8];
    const float* ar2  = (const float*)d_in[9];
    const float* b2   = (const float*)d_in[10];
    float* out = (float*)d_out;

    // workspace layout (4-byte units; ~48 MB total, 16B-aligned sections)
    int*            ideg   = (int*)d_ws;                     // N
    int*            itot   = ideg + NNODES;                  // 4
    int*            irow   = itot + 4;                       // N
    int*            icur   = irow + NNODES;                  // N
    unsigned*       iw1t   = (unsigned*)(icur + NNODES);     // 8192 (W1^T bf16)
    unsigned*       iw2t   = iw1t + 8192;                    // 4096 (W2^T bf16)
    unsigned short* icsr16 = (unsigned short*)(iw2t + 4096); // E ushorts
    unsigned*       gH1    = (unsigned*)(iw2t + 4096 + NEDGES / 2); // N*64 (gemm1 h bf16)
    unsigned*       h1b    = gH1 + (size_t)NNODES * 64;      // N*64 (agg1 h1 bf16)
    float*          hmean  = (float*)(h1b + (size_t)NNODES * 64);   // N*64 f32
    float*          fEl1   = hmean + (size_t)NNODES * 64;    // N*2
    float*          fEr1   = fEl1 + (size_t)NNODES * 2;      // N*2
    unsigned*       gH2    = (unsigned*)(fEr1 + (size_t)NNODES * 2); // N*32
    float*          fEl2   = (float*)(gH2 + (size_t)NNODES * 32);    // N
    float*          fEr2   = fEl2 + (size_t)NNODES;          // N

    // ---- CSR build + weight prep ----
    hipMemsetAsync(ideg, 0, (NNODES + 4) * sizeof(int), stream);
    hist_kernel<<<(NEDGES + 255) / 256, 256, 0, stream>>>(dst, ideg);
    alloc_kernel<<<(NNODES + 255) / 256, 256, 0, stream>>>(ideg, itot, irow, icur);
    fill_kernel<<<(NEDGES + 255) / 256, 256, 0, stream>>>(src, dst, icur, icsr16);
    wt_kernel<<<48, 256, 0, stream>>>(W1, W2, iw1t, iw2t);

    // ---- layer 1 ----
    gemm1_kernel<<<(NNODES + 63) / 64, 256, 0, stream>>>(feat, iw1t, al1, ar1,
                                                         gH1, fEl1, fEr1);
    aggregate1_kernel<<<(NNODES + 3) / 4, 256, 0, stream>>>(
        irow, ideg, icsr16, fEl1, fEr1, gH1, b1, h1b, hmean);

    // ---- layer 2 ----
    gemm2_kernel<<<(NNODES + 63) / 64, 256, 0, stream>>>(h1b, iw2t, al2, ar2,
                                                         gH2, fEl2, fEr2);
    aggregate2_kernel<<<(NNODES / 2 + 3) / 4, 256, 0, stream>>>(
        irow, ideg, icsr16, fEl2, fEr2, gH2, b2, hmean, out);
}

// Round 2
// 262.887 us; speedup vs baseline: 1.0632x; 1.0503x over previous
//
#include <hip/hip_runtime.h>
#include <math.h>

// Problem constants: N=50000, E=800000, IN=128, OUT=64, H1=2, H2=1
#define NNODES 50000
#define NEDGES 800000

typedef short bf16x8 __attribute__((ext_vector_type(8)));
typedef float f32x4  __attribute__((ext_vector_type(4)));

// ---- manual bf16 pack/unpack (plain uint words) ----
__device__ __forceinline__ unsigned bfpack(float a, float b) {
    unsigned ua = __float_as_uint(a), ub = __float_as_uint(b);
    ua = (ua + 0x7fffu + ((ua >> 16) & 1u)) >> 16;
    ub = (ub + 0x7fffu + ((ub >> 16) & 1u)) >> 16;
    return ua | (ub << 16);
}
__device__ __forceinline__ float bflo(unsigned u) { return __uint_as_float(u << 16); }
__device__ __forceinline__ float bfhi(unsigned u) { return __uint_as_float(u & 0xffff0000u); }

// ---------------- CSR build (by dst; shared by both layers) ----------------

__global__ __launch_bounds__(256) void hist_kernel(const int* __restrict__ dst,
                                                   int* __restrict__ deg) {
    int e = blockIdx.x * 256 + threadIdx.x;
    if (e < NEDGES) atomicAdd(&deg[dst[e]], 1);
}

__global__ __launch_bounds__(256) void alloc_kernel(const int* __restrict__ deg,
                                                    int* __restrict__ total,
                                                    int* __restrict__ rowptr,
                                                    int* __restrict__ cursor) {
    const int i = blockIdx.x * 256 + threadIdx.x;
    const int lane = threadIdx.x & 63;
    int d = (i < NNODES) ? deg[i] : 0;
    int incl = d;
#pragma unroll
    for (int off = 1; off < 64; off <<= 1) {
        int t = __shfl_up(incl, off);
        if (lane >= off) incl += t;
    }
    int base = 0;
    if (lane == 63) base = atomicAdd(total, incl);
    base = __shfl(base, 63);
    if (i < NNODES) {
        int pos = base + incl - d;
        rowptr[i] = pos;
        cursor[i] = pos;
    }
}

__global__ __launch_bounds__(256) void fill_kernel(
    const int* __restrict__ src, const int* __restrict__ dst,
    int* __restrict__ cursor, unsigned short* __restrict__ csr_src) {
    int e = blockIdx.x * 256 + threadIdx.x;
    if (e < NEDGES) {
        int pos = atomicAdd(&cursor[dst[e]], 1);
        csr_src[pos] = (unsigned short)src[e];
    }
}

// ---------------- weight prep: W1^T and W2^T packed bf16 -------------------
__global__ __launch_bounds__(256) void wt_kernel(const float* __restrict__ W1,
                                                 const float* __restrict__ W2,
                                                 unsigned* __restrict__ W1t,
                                                 unsigned* __restrict__ W2t) {
    int w = blockIdx.x * 256 + threadIdx.x;   // 0..12287
    if (w < 8192) {
        int n = w >> 6, j = w & 63;
        W1t[w] = bfpack(W1[(2 * j) * 128 + n], W1[(2 * j + 1) * 128 + n]);
    } else {
        int w2 = w - 8192;
        int n = w2 >> 6, j = w2 & 63;
        W2t[w2] = bfpack(W2[(2 * j) * 64 + n], W2[(2 * j + 1) * 64 + n]);
    }
}

// ---------------- gemm1: MFMA bf16 ----------------
__global__ __launch_bounds__(256) void gemm1_kernel(
    const float* __restrict__ feat, const unsigned* __restrict__ Wt,
    const float* __restrict__ al, const float* __restrict__ ar,
    unsigned* __restrict__ h, float* __restrict__ el, float* __restrict__ er) {
    __shared__ unsigned Wb[128 * 68];
    __shared__ unsigned Ab[64 * 68];
    const int tid = threadIdx.x;
    const int n0  = blockIdx.x * 64;

#pragma unroll
    for (int i = 0; i < 8; ++i) {
        int id = i * 256 + tid;
        int n = id >> 4, c = (id & 15) * 4;
        *(uint4*)&Wb[n * 68 + c] = *(const uint4*)&Wt[n * 64 + c];
    }
#pragma unroll
    for (int i = 0; i < 8; ++i) {
        int f = i * 256 + tid;
        int m = f >> 5, cf = (f & 31) * 4;
        float4 v = make_float4(0.f, 0.f, 0.f, 0.f);
        if (n0 + m < NNODES)
            v = *(const float4*)&feat[(size_t)(n0 + m) * 128 + cf];
        uint2 p = {bfpack(v.x, v.y), bfpack(v.z, v.w)};
        *(uint2*)&Ab[m * 68 + cf / 2] = p;
    }
    __syncthreads();

    const int w  = tid >> 6;
    const int l  = tid & 63;
    const int ml = l & 15;
    const int q  = l >> 4;
    f32x4 acc[8];
#pragma unroll
    for (int t = 0; t < 8; ++t) acc[t] = (f32x4){0.f, 0.f, 0.f, 0.f};

#pragma unroll
    for (int kc = 0; kc < 4; ++kc) {
        const int kw = kc * 16 + q * 4;
        uint4 a4 = *(uint4*)&Ab[(16 * w + ml) * 68 + kw];
        bf16x8 af = *(bf16x8*)&a4;
#pragma unroll
        for (int t = 0; t < 8; ++t) {
            uint4 b4 = *(uint4*)&Wb[(t * 16 + ml) * 68 + kw];
            bf16x8 bf = *(bf16x8*)&b4;
            acc[t] = __builtin_amdgcn_mfma_f32_16x16x32_bf16(af, bf, acc[t], 0, 0, 0);
        }
    }

    float av[8], rv[8];
#pragma unroll
    for (int t = 0; t < 8; ++t) { av[t] = al[t * 16 + ml]; rv[t] = ar[t * 16 + ml]; }

#pragma unroll
    for (int r = 0; r < 4; ++r) {
        const int node = n0 + 16 * w + q * 4 + r;
        float e0 = 0.f, e1 = 0.f, f0 = 0.f, f1 = 0.f;
#pragma unroll
        for (int t = 0; t < 8; ++t) {
            float v = acc[t][r];
            if (t < 4) { e0 = fmaf(v, av[t], e0); f0 = fmaf(v, rv[t], f0); }
            else       { e1 = fmaf(v, av[t], e1); f1 = fmaf(v, rv[t], f1); }
            float pv = __shfl_xor(v, 1);
            if ((ml & 1) == 0 && node < NNODES)
                h[(size_t)node * 64 + t * 8 + (ml >> 1)] = bfpack(v, pv);
        }
#pragma unroll
        for (int mm = 1; mm <= 8; mm <<= 1) {
            e0 += __shfl_xor(e0, mm); e1 += __shfl_xor(e1, mm);
            f0 += __shfl_xor(f0, mm); f1 += __shfl_xor(f1, mm);
        }
        if (ml == 0 && node < NNODES) {
            el[node * 2 + 0] = e0; el[node * 2 + 1] = e1;
            er[node * 2 + 0] = f0; er[node * 2 + 1] = f1;
        }
    }
}

// ---------------- gemm2: MFMA bf16, A read directly as packed bf16 ---------
__global__ __launch_bounds__(256) void gemm2_kernel(
    const unsigned* __restrict__ h1b, const unsigned* __restrict__ Wt,
    const float* __restrict__ al, const float* __restrict__ ar,
    unsigned* __restrict__ h2, float* __restrict__ el, float* __restrict__ er) {
    __shared__ unsigned Wb[64 * 68];
    __shared__ unsigned Ab[64 * 68];
    const int tid = threadIdx.x;
    const int n0  = blockIdx.x * 64;

#pragma unroll
    for (int i = 0; i < 4; ++i) {
        int id = i * 256 + tid;
        int n = id >> 4, c = (id & 15) * 4;
        *(uint4*)&Wb[n * 68 + c] = *(const uint4*)&Wt[n * 64 + c];
    }
#pragma unroll
    for (int i = 0; i < 4; ++i) {
        int id = i * 256 + tid;
        int m = id >> 4, c = (id & 15) * 4;
        uint4 v = make_uint4(0u, 0u, 0u, 0u);
        if (n0 + m < NNODES)
            v = *(const uint4*)&h1b[(size_t)(n0 + m) * 64 + c];
        *(uint4*)&Ab[m * 68 + c] = v;
    }
    __syncthreads();

    const int w  = tid >> 6;
    const int l  = tid & 63;
    const int ml = l & 15;
    const int q  = l >> 4;
    f32x4 acc[4];
#pragma unroll
    for (int t = 0; t < 4; ++t) acc[t] = (f32x4){0.f, 0.f, 0.f, 0.f};

#pragma unroll
    for (int kc = 0; kc < 4; ++kc) {
        const int kw = kc * 16 + q * 4;
        uint4 a4 = *(uint4*)&Ab[(16 * w + ml) * 68 + kw];
        bf16x8 af = *(bf16x8*)&a4;
#pragma unroll
        for (int t = 0; t < 4; ++t) {
            uint4 b4 = *(uint4*)&Wb[(t * 16 + ml) * 68 + kw];
            bf16x8 bf = *(bf16x8*)&b4;
            acc[t] = __builtin_amdgcn_mfma_f32_16x16x32_bf16(af, bf, acc[t], 0, 0, 0);
        }
    }

    float av[4], rv[4];
#pragma unroll
    for (int t = 0; t < 4; ++t) { av[t] = al[t * 16 + ml]; rv[t] = ar[t * 16 + ml]; }

#pragma unroll
    for (int r = 0; r < 4; ++r) {
        const int node = n0 + 16 * w + q * 4 + r;
        float e0 = 0.f, f0 = 0.f;
#pragma unroll
        for (int t = 0; t < 4; ++t) {
            float v = acc[t][r];
            e0 = fmaf(v, av[t], e0);
            f0 = fmaf(v, rv[t], f0);
            float pv = __shfl_xor(v, 1);
            if ((ml & 1) == 0 && node < NNODES)
                h2[(size_t)node * 32 + t * 8 + (ml >> 1)] = bfpack(v, pv);
        }
#pragma unroll
        for (int mm = 1; mm <= 8; mm <<= 1) {
            e0 += __shfl_xor(e0, mm);
            f0 += __shfl_xor(f0, mm);
        }
        if (ml == 0 && node < NNODES) { el[node] = e0; er[node] = f0; }
    }
}

#define FMA8(hv, A)                                              \
    a0r = fmaf(A, bflo(hv.x), a0r); a1r = fmaf(A, bfhi(hv.x), a1r); \
    a2r = fmaf(A, bflo(hv.y), a2r); a3r = fmaf(A, bfhi(hv.y), a3r); \
    a4r = fmaf(A, bflo(hv.z), a4r); a5r = fmaf(A, bfhi(hv.z), a5r); \
    a6r = fmaf(A, bflo(hv.w), a6r); a7r = fmaf(A, bfhi(hv.w), a7r);

// ---- layer-1 aggregate: TWO nodes/wave (32 lanes each).
// Key: hh-gather for edges 0..15 is issued BEFORE the softmax phase (its
// addresses depend only on csr_src), so the gather latency hides under the
// max/exp/sum reduction chain. Phantom edges (lane >= deg) have s=0 / p=0:
// loads hit row 0 (cache-hot), FMAs add 0.
__global__ __launch_bounds__(256) void aggregate1_kernel(
    const int* __restrict__ rowptr, const int* __restrict__ degv,
    const unsigned short* __restrict__ csr_src,
    const float* __restrict__ el, const float* __restrict__ er,
    const unsigned* __restrict__ hh, const float* __restrict__ bias,
    unsigned* __restrict__ h1b, float* __restrict__ hm) {
    const int wid  = (blockIdx.x * 256 + threadIdx.x) >> 6;
    const int lane = threadIdx.x & 63;
    const int hl   = lane & 31;
    const int lb   = lane & 32;
    const int node = wid * 2 + (lane >> 5);
    if (node >= NNODES) return;
    const int row = rowptr[node];
    const int deg = degv[node];
    const float er0 = er[node * 2 + 0];
    const float er1 = er[node * 2 + 1];

    const int  q2    = hl >> 4;        // edge parity within pair
    const int  ql    = hl & 15;        // dim chunk (4 uints = 8 bf16)
    const bool h1sel = (ql >= 8);
    const unsigned* __restrict__ hq = hh + 4 * ql;

    int s_reg = 0;
    if (hl < deg) s_reg = (int)csr_src[row + hl];

    // ---- prefetch batch A: edges 0..15, 8 gathers in flight per lane ----
    uint4 hv[8];
#pragma unroll
    for (int j = 0; j < 8; ++j) {
        int s = __shfl(s_reg, lb + 2 * j + q2);
        hv[j] = *(const uint4*)(hq + (size_t)s * 64);
    }

    // ---- softmax phase (overlaps batch-A load latency) ----
    float2 e2 = *(const float2*)&el[s_reg * 2];
    float a = e2.x + er0; a = a > 0.f ? a : 0.2f * a;
    float b = e2.y + er1; b = b > 0.f ? b : 0.2f * b;
    float v0 = (hl < deg) ? a : -1e30f;
    float v1 = (hl < deg) ? b : -1e30f;
    float m0 = v0, m1 = v1;
    for (int i = 32 + hl; i < deg; i += 32) {       // rare: deg > 32
        int s = (int)csr_src[row + i];
        float2 ee = *(const float2*)&el[s * 2];
        float aa = ee.x + er0; aa = aa > 0.f ? aa : 0.2f * aa;
        float bb = ee.y + er1; bb = bb > 0.f ? bb : 0.2f * bb;
        m0 = fmaxf(m0, aa); m1 = fmaxf(m1, bb);
    }
#pragma unroll
    for (int off = 16; off > 0; off >>= 1) {
        m0 = fmaxf(m0, __shfl_xor(m0, off));
        m1 = fmaxf(m1, __shfl_xor(m1, off));
    }
    float p0 = __expf(v0 - m0);    // phantom lanes: exp(-huge) = 0
    float p1 = __expf(v1 - m1);
    float ssum0 = p0, ssum1 = p1;
    for (int i = 32 + hl; i < deg; i += 32) {       // rare: deg > 32
        int s = (int)csr_src[row + i];
        float2 ee = *(const float2*)&el[s * 2];
        float aa = ee.x + er0; aa = aa > 0.f ? aa : 0.2f * aa;
        float bb = ee.y + er1; bb = bb > 0.f ? bb : 0.2f * bb;
        ssum0 += __expf(aa - m0); ssum1 += __expf(bb - m1);
    }
#pragma unroll
    for (int off = 16; off > 0; off >>= 1) {
        ssum0 += __shfl_xor(ssum0, off);
        ssum1 += __shfl_xor(ssum1, off);
    }

    // ---- batch A FMAs ----
    float a0r = 0.f, a1r = 0.f, a2r = 0.f, a3r = 0.f;
    float a4r = 0.f, a5r = 0.f, a6r = 0.f, a7r = 0.f;
#pragma unroll
    for (int j = 0; j < 8; ++j) {
        const int sl_ = lb + 2 * j + q2;
        float x = __shfl(p0, sl_);
        float y = __shfl(p1, sl_);
        float A = h1sel ? y : x;
        FMA8(hv[j], A)
    }
    // ---- batch B: edges 16..31 (wave-uniform skip) ----
    int dm  = deg < 32 ? deg : 32;
    int dmW = max(dm, __shfl_xor(dm, 32));
    if (dmW > 16) {
#pragma unroll
        for (int j = 0; j < 8; ++j) {
            const int sl_ = lb + 16 + 2 * j + q2;
            int s = __shfl(s_reg, sl_);
            uint4 h4 = *(const uint4*)(hq + (size_t)s * 64);
            float x = __shfl(p0, sl_);
            float y = __shfl(p1, sl_);
            float A = h1sel ? y : x;
            FMA8(h4, A)
        }
    }
    // ---- tail: deg > 32 (rare) ----
    for (int i2 = 32; i2 < deg; i2 += 2) {
        int eidx = i2 + q2;
        if (eidx < deg) {
            int s = (int)csr_src[row + eidx];
            float2 ee = *(const float2*)&el[s * 2];
            float aa = ee.x + er0; aa = aa > 0.f ? aa : 0.2f * aa;
            float bb = ee.y + er1; bb = bb > 0.f ? bb : 0.2f * bb;
            float alpha = h1sel ? __expf(bb - m1) : __expf(aa - m0);
            uint4 h4 = *(const uint4*)(hq + (size_t)s * 64);
            FMA8(h4, alpha)
        }
    }
    // reduce across the q2 pair (single stage)
    a0r += __shfl_xor(a0r, 16);  a1r += __shfl_xor(a1r, 16);
    a2r += __shfl_xor(a2r, 16);  a3r += __shfl_xor(a3r, 16);
    a4r += __shfl_xor(a4r, 16);  a5r += __shfl_xor(a5r, 16);
    a6r += __shfl_xor(a6r, 16);  a7r += __shfl_xor(a7r, 16);

    // ---- epilogue ----
    const float ssum = h1sel ? ssum1 : ssum0;
    const float inv  = (deg > 0) ? 1.f / ssum : 0.f;
    float4 b0 = *(const float4*)&bias[8 * ql];
    float4 b1 = *(const float4*)&bias[8 * ql + 4];
    float o0 = fmaf(a0r, inv, b0.x), o1 = fmaf(a1r, inv, b0.y);
    float o2 = fmaf(a2r, inv, b0.z), o3 = fmaf(a3r, inv, b0.w);
    float o4 = fmaf(a4r, inv, b1.x), o5 = fmaf(a5r, inv, b1.y);
    float o6 = fmaf(a6r, inv, b1.z), o7 = fmaf(a7r, inv, b1.w);
    o0 = o0 > 0.f ? o0 : (__expf(o0) - 1.f);
    o1 = o1 > 0.f ? o1 : (__expf(o1) - 1.f);
    o2 = o2 > 0.f ? o2 : (__expf(o2) - 1.f);
    o3 = o3 > 0.f ? o3 : (__expf(o3) - 1.f);
    o4 = o4 > 0.f ? o4 : (__expf(o4) - 1.f);
    o5 = o5 > 0.f ? o5 : (__expf(o5) - 1.f);
    o6 = o6 > 0.f ? o6 : (__expf(o6) - 1.f);
    o7 = o7 > 0.f ? o7 : (__expf(o7) - 1.f);

    if (hl < 16) {
        uint4 pk;
        pk.x = bfpack(o0, o1); pk.y = bfpack(o2, o3);
        pk.z = bfpack(o4, o5); pk.w = bfpack(o6, o7);
        *(uint4*)&h1b[(size_t)node * 64 + 4 * ql] = pk;
    }
    // head mean: dim lane ql pairs with ql^8 (head 1 holds dims 64..127)
    float n0_ = 0.5f * (o0 + __shfl_xor(o0, 8));
    float n1_ = 0.5f * (o1 + __shfl_xor(o1, 8));
    float n2_ = 0.5f * (o2 + __shfl_xor(o2, 8));
    float n3_ = 0.5f * (o3 + __shfl_xor(o3, 8));
    float n4_ = 0.5f * (o4 + __shfl_xor(o4, 8));
    float n5_ = 0.5f * (o5 + __shfl_xor(o5, 8));
    float n6_ = 0.5f * (o6 + __shfl_xor(o6, 8));
    float n7_ = 0.5f * (o7 + __shfl_xor(o7, 8));
    if (hl < 8) {
        *(float4*)&hm[(size_t)node * 64 + 8 * hl]     = make_float4(n0_, n1_, n2_, n3_);
        *(float4*)&hm[(size_t)node * 64 + 8 * hl + 4] = make_float4(n4_, n5_, n6_, n7_);
    }
}

#define FMA4(hv, P)                                            \
    ax = fmaf(P, bflo(hv.x), ax); ay = fmaf(P, bfhi(hv.x), ay); \
    az = fmaf(P, bflo(hv.y), az); aw = fmaf(P, bfhi(hv.y), aw);

// ---- layer-2 aggregate: same structure (2 nodes/wave, gather prefetch) ----
__global__ __launch_bounds__(256) void aggregate2_kernel(
    const int* __restrict__ rowptr, const int* __restrict__ degv,
    const unsigned short* __restrict__ csr_src,
    const float* __restrict__ el, const float* __restrict__ er,
    const unsigned* __restrict__ hh, const float* __restrict__ bias,
    const float* __restrict__ hm, float* __restrict__ outp) {
    const int wid  = (blockIdx.x * 256 + threadIdx.x) >> 6;
    const int lane = threadIdx.x & 63;
    const int hl   = lane & 31;
    const int lb   = lane & 32;
    const int node = wid * 2 + (lane >> 5);
    if (node >= NNODES) return;
    const int row = rowptr[node];
    const int deg = degv[node];
    const float erd = er[node];

    const int s2 = hl >> 4;
    const int sl = hl & 15;
    const unsigned* __restrict__ hq = hh + 2 * sl;

    int s_reg = 0;
    if (hl < deg) s_reg = (int)csr_src[row + hl];

    // prefetch batch A: edges 0..15
    uint2 hv[8];
#pragma unroll
    for (int j = 0; j < 8; ++j) {
        int s = __shfl(s_reg, lb + 2 * j + s2);
        hv[j] = *(const uint2*)(hq + (size_t)s * 32);
    }

    float v = el[s_reg] + erd;
    v = v > 0.f ? v : 0.2f * v;
    float v_reg = (hl < deg) ? v : -1e30f;
    float m = v_reg;
    for (int i = 32 + hl; i < deg; i += 32) {
        int s = (int)csr_src[row + i];
        float vv = el[s] + erd;
        vv = vv > 0.f ? vv : 0.2f * vv;
        m = fmaxf(m, vv);
    }
#pragma unroll
    for (int off = 16; off > 0; off >>= 1) m = fmaxf(m, __shfl_xor(m, off));

    float p_reg = __expf(v_reg - m);
    float ssum = p_reg;
    for (int i = 32 + hl; i < deg; i += 32) {
        int s = (int)csr_src[row + i];
        float vv = el[s] + erd;
        vv = vv > 0.f ? vv : 0.2f * vv;
        ssum += __expf(vv - m);
    }
#pragma unroll
    for (int off = 16; off > 0; off >>= 1) ssum += __shfl_xor(ssum, off);

    float ax = 0.f, ay = 0.f, az = 0.f, aw = 0.f;
#pragma unroll
    for (int j = 0; j < 8; ++j) {
        const int sl_ = lb + 2 * j + s2;
        float p = __shfl(p_reg, sl_);
        FMA4(hv[j], p)
    }
    int dm  = deg < 32 ? deg : 32;
    int dmW = max(dm, __shfl_xor(dm, 32));
    if (dmW > 16) {
#pragma unroll
        for (int j = 0; j < 8; ++j) {
            const int sl_ = lb + 16 + 2 * j + s2;
            int s = __shfl(s_reg, sl_);
            uint2 h2v = *(const uint2*)(hq + (size_t)s * 32);
            float p = __shfl(p_reg, sl_);
            FMA4(h2v, p)
        }
    }
    for (int i2 = 32; i2 < deg; i2 += 2) {
        int eidx = i2 + s2;
        if (eidx < deg) {
            int s = (int)csr_src[row + eidx];
            float vv = el[s] + erd;
            vv = vv > 0.f ? vv : 0.2f * vv;
            float p = __expf(vv - m);
            uint2 h2v = *(const uint2*)(hq + (size_t)s * 32);
            FMA4(h2v, p)
        }
    }
    ax += __shfl_xor(ax, 16);  ay += __shfl_xor(ay, 16);
    az += __shfl_xor(az, 16);  aw += __shfl_xor(aw, 16);

    if (sl == hl) {
        float inv = (deg > 0) ? 1.f / ssum : 0.f;
        float4 hmv = *(const float4*)&hm[(size_t)node * 64 + 4 * sl];
        float4 bb  = *(const float4*)&bias[4 * sl];
        float o0 = (hmv.x + fmaf(ax, inv, bb.x)) * 0.5f;
        float o1 = (hmv.y + fmaf(ay, inv, bb.y)) * 0.5f;
        float o2 = (hmv.z + fmaf(az, inv, bb.z)) * 0.5f;
        float o3 = (hmv.w + fmaf(aw, inv, bb.w)) * 0.5f;
        *(float4*)&outp[(size_t)node * 64 + 4 * sl] = make_float4(o0, o1, o2, o3);
    }
}

// ---------------- launcher ----------------

extern "C" void kernel_launch(void* const* d_in, const int* in_sizes, int n_in,
                              void* d_out, int out_size, void* d_ws, size_t ws_size,
                              hipStream_t stream) {
    const float* feat = (const float*)d_in[0];
    const int*   src  = (const int*)d_in[1];
    const int*   dst  = (const int*)d_in[2];
    const float* W1   = (const float*)d_in[3];
    const float* al1  = (const float*)d_in[4];
    const float* ar1  = (const float*)d_in[5];
    const float* b1   = (const float*)d_in[6];
    const float* W2   = (const float*)d_in[7];
    const float* al2  = (const float*)d_in[8];
    const float* ar2  = (const float*)d_in[9];
    const float* b2   = (const float*)d_in[10];
    float* out = (float*)d_out;

    // workspace layout (4-byte units; ~48 MB total, 16B-aligned sections)
    int*            ideg   = (int*)d_ws;                     // N
    int*            itot   = ideg + NNODES;                  // 4
    int*            irow   = itot + 4;                       // N
    int*            icur   = irow + NNODES;                  // N
    unsigned*       iw1t   = (unsigned*)(icur + NNODES);     // 8192 (W1^T bf16)
    unsigned*       iw2t   = iw1t + 8192;                    // 4096 (W2^T bf16)
    unsigned short* icsr16 = (unsigned short*)(iw2t + 4096); // E ushorts
    unsigned*       gH1    = (unsigned*)(iw2t + 4096 + NEDGES / 2); // N*64 (gemm1 h bf16)
    unsigned*       h1b    = gH1 + (size_t)NNODES * 64;      // N*64 (agg1 h1 bf16)
    float*          hmean  = (float*)(h1b + (size_t)NNODES * 64);   // N*64 f32
    float*          fEl1   = hmean + (size_t)NNODES * 64;    // N*2
    float*          fEr1   = fEl1 + (size_t)NNODES * 2;      // N*2
    unsigned*       gH2    = (unsigned*)(fEr1 + (size_t)NNODES * 2); // N*32
    float*          fEl2   = (float*)(gH2 + (size_t)NNODES * 32);    // N
    float*          fEr2   = fEl2 + (size_t)NNODES;          // N

    // ---- CSR build + weight prep ----
    hipMemsetAsync(ideg, 0, (NNODES + 4) * sizeof(int), stream);
    hist_kernel<<<(NEDGES + 255) / 256, 256, 0, stream>>>(dst, ideg);
    alloc_kernel<<<(NNODES + 255) / 256, 256, 0, stream>>>(ideg, itot, irow, icur);
    fill_kernel<<<(NEDGES + 255) / 256, 256, 0, stream>>>(src, dst, icur, icsr16);
    wt_kernel<<<48, 256, 0, stream>>>(W1, W2, iw1t, iw2t);

    // ---- layer 1 ----
    gemm1_kernel<<<(NNODES + 63) / 64, 256, 0, stream>>>(feat, iw1t, al1, ar1,
                                                         gH1, fEl1, fEr1);
    aggregate1_kernel<<<(NNODES / 2 + 3) / 4, 256, 0, stream>>>(
        irow, ideg, icsr16, fEl1, fEr1, gH1, b1, h1b, hmean);

    // ---- layer 2 ----
    gemm2_kernel<<<(NNODES + 63) / 64, 256, 0, stream>>>(h1b, iw2t, al2, ar2,
                                                         gH2, fEl2, fEr2);
    aggregate2_kernel<<<(NNODES / 2 + 3) / 4, 256, 0, stream>>>(
        irow, ideg, icsr16, fEl2, fEr2, gH2, b2, hmean, out);
}